// Round 10
// baseline (475.272 us; speedup 1.0000x reference)
//
#include <hip/hip_runtime.h>
#include <math.h>

typedef __attribute__((ext_vector_type(4))) float f32x4;
typedef __attribute__((ext_vector_type(8))) short bf16x8;

__device__ __forceinline__ unsigned short f2bf(float f) {
  unsigned int u = __builtin_bit_cast(unsigned int, f);
  u += 0x7FFFu + ((u >> 16) & 1u);
  return (unsigned short)(u >> 16);
}

__device__ __forceinline__ f32x4 mfma16(bf16x8 a, bf16x8 b, f32x4 c) {
  return __builtin_amdgcn_mfma_f32_16x16x32_bf16(a, b, c, 0, 0, 0);
}

// ---------------- prep: fold BN into W (bf16) + bias (f32) ----------------
__global__ void prep_kernel(const float* __restrict__ W, const float* __restrict__ g,
                            const float* __restrict__ bb, const float* __restrict__ mm,
                            const float* __restrict__ vv,
                            unsigned short* __restrict__ Wout, float* __restrict__ bout,
                            float alpha) {
  int idx = blockIdx.x * 256 + threadIdx.x;
  if (idx < 192 * 192) {
    int o = idx / 192;
    float s = g[o] * rsqrtf(vv[o] + 1e-5f);
    Wout[idx] = f2bf(W[idx] * s * alpha);
  }
  if (idx < 192) {
    float s = g[idx] * rsqrtf(vv[idx] + 1e-5f);
    bout[idx] = (bb[idx] - mm[idx] * s) * alpha;
  }
}

// ---------------- projection: Y = relu(W' X + bias) ----------------
// X: [B][192][4096] f32.  LAYOUT 0: Y[b][o][hw] bf16; LAYOUT 1: Y[b][hw][o] bf16.
template <int LAYOUT>
__launch_bounds__(256)
__global__ void proj_kernel(const float* __restrict__ X,
                            const unsigned short* __restrict__ Wp,
                            const float* __restrict__ bias,
                            unsigned short* __restrict__ Yv) {
  const int o0 = blockIdx.x * 64;
  const int hw0 = blockIdx.y * 64;
  const int b = blockIdx.z;
  const int w = threadIdx.x >> 6, l = threadIdx.x & 63;
  const int l16 = l & 15, lg = l >> 4;
  const float* Xb = X + (size_t)b * 192 * 4096;

  f32x4 acc[4] = {f32x4{0,0,0,0}, f32x4{0,0,0,0}, f32x4{0,0,0,0}, f32x4{0,0,0,0}};

  for (int ks = 0; ks < 6; ++ks) {
    const int c0 = ks * 32 + lg * 8;
    bf16x8 a = *(const bf16x8*)(Wp + (size_t)(o0 + 16 * w + l16) * 192 + c0);
#pragma unroll
    for (int n = 0; n < 4; ++n) {
      const int hw = hw0 + 16 * n + l16;
      bf16x8 bfr;
#pragma unroll
      for (int j = 0; j < 8; ++j)
        bfr[j] = (short)f2bf(Xb[(size_t)(c0 + j) * 4096 + hw]);
      acc[n] = mfma16(a, bfr, acc[n]);
    }
  }

#pragma unroll
  for (int n = 0; n < 4; ++n) {
    const int hw = hw0 + 16 * n + l16;
    float vv4[4];
#pragma unroll
    for (int r = 0; r < 4; ++r) {
      const int o = o0 + 16 * w + lg * 4 + r;
      vv4[r] = fmaxf(acc[n][r] + bias[o], 0.0f);
    }
    if (LAYOUT == 1) {
      unsigned int lo = (unsigned)f2bf(vv4[0]) | ((unsigned)f2bf(vv4[1]) << 16);
      unsigned int hi = (unsigned)f2bf(vv4[2]) | ((unsigned)f2bf(vv4[3]) << 16);
      uint2 pk; pk.x = lo; pk.y = hi;
      *(uint2*)(Yv + ((size_t)b * 4096 + hw) * 192 + o0 + 16 * w + lg * 4) = pk;
    } else {
#pragma unroll
      for (int r = 0; r < 4; ++r) {
        const int o = o0 + 16 * w + lg * 4 + r;
        Yv[((size_t)b * 192 + o) * 4096 + hw] = f2bf(vv4[r]);
      }
    }
  }
}

// ---------------- final projection with NS-way partial-sum input (f32 out) ----------------
template <int NS>
__launch_bounds__(256)
__global__ void proj_sum_kernel(const float* __restrict__ X,
                                const unsigned short* __restrict__ Wp,
                                const float* __restrict__ bias,
                                float* __restrict__ Yv) {
  const int o0 = blockIdx.x * 64;
  const int hw0 = blockIdx.y * 64;
  const int b = blockIdx.z;
  const int w = threadIdx.x >> 6, l = threadIdx.x & 63;
  const int l16 = l & 15, lg = l >> 4;
  const float* Xb = X + (size_t)b * 192 * 4096;
  const size_t sstride = (size_t)4 * 192 * 4096;

  f32x4 acc[4] = {f32x4{0,0,0,0}, f32x4{0,0,0,0}, f32x4{0,0,0,0}, f32x4{0,0,0,0}};

  for (int ks = 0; ks < 6; ++ks) {
    const int c0 = ks * 32 + lg * 8;
    bf16x8 a = *(const bf16x8*)(Wp + (size_t)(o0 + 16 * w + l16) * 192 + c0);
#pragma unroll
    for (int n = 0; n < 4; ++n) {
      const int hw = hw0 + 16 * n + l16;
      bf16x8 bfr;
#pragma unroll
      for (int j = 0; j < 8; ++j) {
        float s = Xb[(size_t)(c0 + j) * 4096 + hw];
#pragma unroll
        for (int ss = 1; ss < NS; ++ss)
          s += Xb[(size_t)(c0 + j) * 4096 + hw + ss * sstride];
        bfr[j] = (short)f2bf(s);
      }
      acc[n] = mfma16(a, bfr, acc[n]);
    }
  }

#pragma unroll
  for (int n = 0; n < 4; ++n) {
    const int hw = hw0 + 16 * n + l16;
#pragma unroll
    for (int r = 0; r < 4; ++r) {
      const int o = o0 + 16 * w + lg * 4 + r;
      Yv[((size_t)b * 192 + o) * 4096 + hw] = fmaxf(acc[n][r] + bias[o], 0.0f);
    }
  }
}

// ---------------- pass 1: colsum[b][k] = sum_q exp2(S[q][k]) ----------------
__launch_bounds__(256)
__global__ void pass1_kernel(const unsigned short* __restrict__ qp,
                             const unsigned short* __restrict__ kpT,
                             float* __restrict__ colsum) {
  const int q0 = blockIdx.x * 128, k0 = blockIdx.y * 128, b = blockIdx.z;
  const int w = threadIdx.x >> 6, l = threadIdx.x & 63;
  const int l16 = l & 15, lg = l >> 4;
  const unsigned short* qb = qp + (size_t)b * 4096 * 192;
  const unsigned short* kb = kpT + (size_t)b * 4096 * 192;

  __shared__ __align__(16) unsigned short kpl[128][200];
  __shared__ float cs[4][128];

  {
    const int t = threadIdx.x;
#pragma unroll
    for (int i = 0; i < 12; ++i) {
      int idx = t + i * 256;
      int row = idx / 24, cu = idx % 24;
      uint4 vdat = *(const uint4*)(kb + (size_t)(k0 + row) * 192 + cu * 8);
      *(uint4*)&kpl[row][cu * 8] = vdat;
    }
  }
  __syncthreads();

  f32x4 acc[2][8];
#pragma unroll
  for (int m = 0; m < 2; ++m)
#pragma unroll
    for (int n = 0; n < 8; ++n) acc[m][n] = f32x4{0, 0, 0, 0};

  for (int ks = 0; ks < 6; ++ks) {
    const int c0 = ks * 32 + lg * 8;
    bf16x8 a0 = *(const bf16x8*)(qb + (size_t)(q0 + 32 * w + l16) * 192 + c0);
    bf16x8 a1 = *(const bf16x8*)(qb + (size_t)(q0 + 32 * w + 16 + l16) * 192 + c0);
#pragma unroll
    for (int n = 0; n < 8; ++n) {
      bf16x8 bfr = *(const bf16x8*)&kpl[16 * n + l16][c0];
      acc[0][n] = mfma16(a0, bfr, acc[0][n]);
      acc[1][n] = mfma16(a1, bfr, acc[1][n]);
    }
  }

  float part[8];
#pragma unroll
  for (int n = 0; n < 8; ++n) {
    float s = 0.f;
#pragma unroll
    for (int r = 0; r < 4; ++r)
      s += __builtin_amdgcn_exp2f(acc[0][n][r]) + __builtin_amdgcn_exp2f(acc[1][n][r]);
    s += __shfl_xor(s, 16);
    s += __shfl_xor(s, 32);
    part[n] = s;
  }
  if (l < 16) {
#pragma unroll
    for (int n = 0; n < 8; ++n) cs[w][16 * n + l] = part[n];
  }
  __syncthreads();
  const int t = threadIdx.x;
  if (t < 128) {
    float s = cs[0][t] + cs[1][t] + cs[2][t] + cs[3][t];
    atomicAdd(&colsum[(size_t)b * 4096 + k0 + t], s);
  }
}

__global__ void invert_kernel(float* __restrict__ p, int n) {
  int i = blockIdx.x * 256 + threadIdx.x;
  if (i < n) p[i] = 1.0f / p[i];
}

// ---------------- pass 2: wave-autonomous, barrier-free ----------------
// Block = 4 waves; each wave owns a PRIVATE 16q x 64k tile: full QK^T for its
// rows, exp2*rcol, private LDS slice (stride 76 f32 vs bank aliasing), corr
// store (256B-contiguous per 16 lanes), PV over all 192 c. Intra-wave LDS
// transpose needs NO barrier (wave-internal lgkmcnt order). Zero s_barrier.
template <int NS>
__launch_bounds__(256, 4)
__global__ void pass2_kernel(const unsigned short* __restrict__ qp,
                             const unsigned short* __restrict__ kpT,
                             const unsigned short* __restrict__ vpN,
                             const float* __restrict__ rcol,
                             float* __restrict__ corr,
                             float* __restrict__ ssP) {
  const int wl = threadIdx.x >> 6, l = threadIdx.x & 63;
  const int l16 = l & 15, lg = l >> 4;
  const int s = blockIdx.y, b = blockIdx.z;
  const int qw = blockIdx.x * 64 + wl * 16;  // wave's 16 q rows
  const int kc0 = s * (64 / NS);             // 64-col k chunks

  const unsigned short* qb = qp + (size_t)b * 4096 * 192;
  const unsigned short* kb = kpT + (size_t)b * 4096 * 192;
  const unsigned short* vb = vpN + (size_t)b * 192 * 4096;
  const float* rc = rcol + (size_t)b * 4096;
  float* corb = corr + (size_t)b * 4096 * 4096;
  float* ssb = ssP + (size_t)(s * 4 + b) * 192 * 4096;

  __shared__ __align__(16) float corAll[4][16][76];  // per-wave private slices
  float (*cor)[76] = corAll[wl];

  // preload A (q) fragments: 24 VGPR, chunk-invariant
  bf16x8 af[6];
#pragma unroll
  for (int ks = 0; ks < 6; ++ks)
    af[ks] = *(const bf16x8*)(qb + (size_t)(qw + l16) * 192 + ks * 32 + lg * 8);

  f32x4 ssa[12];
#pragma unroll
  for (int ct = 0; ct < 12; ++ct) ssa[ct] = f32x4{0, 0, 0, 0};

  for (int kc = kc0; kc < kc0 + 64 / NS; ++kc) {
    const int k0 = kc * 64;

    // ---- QK^T: S[16q x 64k] ----
    f32x4 sa[4];
#pragma unroll
    for (int tn = 0; tn < 4; ++tn) sa[tn] = f32x4{0, 0, 0, 0};
    for (int ks = 0; ks < 6; ++ks) {
      const int c0 = ks * 32 + lg * 8;
#pragma unroll
      for (int tn = 0; tn < 4; ++tn) {
        bf16x8 kf = *(const bf16x8*)(kb + (size_t)(k0 + tn * 16 + l16) * 192 + c0);
        sa[tn] = mfma16(af[ks], kf, sa[tn]);
      }
    }

    // ---- exp2 * rcol -> private LDS tile (q=lg*4+r rows, k=tn*16+l16 cols) ----
#pragma unroll
    for (int tn = 0; tn < 4; ++tn) {
      const float rcv = rc[k0 + tn * 16 + l16];
#pragma unroll
      for (int r = 0; r < 4; ++r)
        cor[lg * 4 + r][tn * 16 + l16] = __builtin_amdgcn_exp2f(sa[tn][r]) * rcv;
    }

    // ---- corr tile -> global (16 lanes = 256B contiguous per row) ----
#pragma unroll
    for (int it = 0; it < 4; ++it) {
      const int row = lg + it * 4;
      f32x4 v4 = *(const f32x4*)&cor[row][l16 * 4];
      __builtin_nontemporal_store(v4, (f32x4*)(corb + (size_t)(qw + row) * 4096 + k0 + l16 * 4));
    }

    // ---- PV: ss[16q x 192c] += P[16q x 64k] @ V[64k x 192c] ----
#pragma unroll
    for (int ks2 = 0; ks2 < 2; ++ks2) {
      const int cc = ks2 * 32 + lg * 8;
      f32x4 p0 = *(const f32x4*)&cor[l16][cc];
      f32x4 p1 = *(const f32x4*)&cor[l16][cc + 4];
      bf16x8 pa;
#pragma unroll
      for (int j = 0; j < 4; ++j) {
        pa[j] = (short)f2bf(p0[j]);
        pa[j + 4] = (short)f2bf(p1[j]);
      }
#pragma unroll
      for (int ct = 0; ct < 12; ++ct) {
        bf16x8 vf = *(const bf16x8*)(vb + (size_t)(ct * 16 + l16) * 4096 + k0 + cc);
        ssa[ct] = mfma16(pa, vf, ssa[ct]);
      }
    }
  }

  // ---- store ss partial (transposed, f32x4 along q) into split slab ----
#pragma unroll
  for (int ct = 0; ct < 12; ++ct)
    *(f32x4*)&ssb[(size_t)(ct * 16 + l16) * 4096 + qw + lg * 4] = ssa[ct];
}

// ---------------- launcher ----------------
extern "C" void kernel_launch(void* const* d_in, const int* in_sizes, int n_in,
                              void* d_out, int out_size, void* d_ws, size_t ws_size,
                              hipStream_t stream) {
  (void)in_sizes; (void)n_in; (void)out_size;
  const float* lr = (const float*)d_in[0];
  const float* refine = (const float*)d_in[1];

  char* ws = (char*)d_ws;
  unsigned short* w4 = (unsigned short*)(ws + 0);                       // 4*192*192 bf16
  float* bias4 = (float*)(ws + 294912);                                // 4*192 f32
  unsigned short* qp = (unsigned short*)(ws + 297984);                 // [4][4096][192] bf16
  unsigned short* kp = (unsigned short*)(ws + 297984 + 6291456);       // [4][4096][192] bf16
  unsigned short* vp = (unsigned short*)(ws + 297984 + 2 * 6291456);   // [4][192][4096] bf16
  float* colsum = (float*)(ws + 297984 + 3 * 6291456);                 // [4][4096] f32
  float* ssP = (float*)(ws + 297984 + 3 * 6291456 + 65536);            // [NS][4][192][4096] f32

  const size_t base = 297984 + (size_t)3 * 6291456 + 65536;
  const size_t slab = (size_t)4 * 192 * 4096 * 4;  // 12.58 MB per split
  int NS = 1;
  if (ws_size >= base + 4 * slab) NS = 4;
  else if (ws_size >= base + 2 * slab) NS = 2;

  float* out0 = (float*)d_out;
  float* corr = out0 + 3145728;  // [4][4096][4096] f32

  const float alpha = (float)(1.4426950408889634 / sqrt(192.0));  // log2(e)/sqrt(C)

  for (int p = 0; p < 4; ++p) {
    prep_kernel<<<dim3(144), dim3(256), 0, stream>>>(
        (const float*)d_in[2 + 5 * p], (const float*)d_in[3 + 5 * p],
        (const float*)d_in[4 + 5 * p], (const float*)d_in[5 + 5 * p],
        (const float*)d_in[6 + 5 * p],
        w4 + p * 36864, bias4 + p * 192, p == 0 ? alpha : 1.0f);
  }
  hipMemsetAsync(colsum, 0, 65536, stream);

  proj_kernel<1><<<dim3(3, 64, 4), dim3(256), 0, stream>>>(refine, w4, bias4, qp);
  proj_kernel<1><<<dim3(3, 64, 4), dim3(256), 0, stream>>>(lr, w4 + 36864, bias4 + 192, kp);
  proj_kernel<0><<<dim3(3, 64, 4), dim3(256), 0, stream>>>(lr, w4 + 2 * 36864, bias4 + 2 * 192, vp);

  pass1_kernel<<<dim3(32, 32, 4), dim3(256), 0, stream>>>(qp, kp, colsum);
  invert_kernel<<<dim3(64), dim3(256), 0, stream>>>(colsum, 16384);

  if (NS == 4) {
    pass2_kernel<4><<<dim3(64, 4, 4), dim3(256), 0, stream>>>(qp, kp, vp, colsum, corr, ssP);
    proj_sum_kernel<4><<<dim3(3, 64, 4), dim3(256), 0, stream>>>(ssP, w4 + 3 * 36864, bias4 + 3 * 192, out0);
  } else if (NS == 2) {
    pass2_kernel<2><<<dim3(64, 2, 4), dim3(256), 0, stream>>>(qp, kp, vp, colsum, corr, ssP);
    proj_sum_kernel<2><<<dim3(3, 64, 4), dim3(256), 0, stream>>>(ssP, w4 + 3 * 36864, bias4 + 3 * 192, out0);
  } else {
    pass2_kernel<1><<<dim3(64, 1, 4), dim3(256), 0, stream>>>(qp, kp, vp, colsum, corr, ssP);
    proj_sum_kernel<1><<<dim3(3, 64, 4), dim3(256), 0, stream>>>(ssP, w4 + 3 * 36864, bias4 + 3 * 192, out0);
  }
}

// Round 11
// 334.183 us; speedup vs baseline: 1.4222x; 1.4222x over previous
//
#include <hip/hip_runtime.h>
#include <math.h>

typedef __attribute__((ext_vector_type(4))) float f32x4;
typedef __attribute__((ext_vector_type(8))) short bf16x8;

__device__ __forceinline__ unsigned short f2bf(float f) {
  unsigned int u = __builtin_bit_cast(unsigned int, f);
  u += 0x7FFFu + ((u >> 16) & 1u);
  return (unsigned short)(u >> 16);
}

__device__ __forceinline__ f32x4 mfma16(bf16x8 a, bf16x8 b, f32x4 c) {
  return __builtin_amdgcn_mfma_f32_16x16x32_bf16(a, b, c, 0, 0, 0);
}

// ---------------- prep: fold BN into W (bf16) + bias (f32) ----------------
__global__ void prep_kernel(const float* __restrict__ W, const float* __restrict__ g,
                            const float* __restrict__ bb, const float* __restrict__ mm,
                            const float* __restrict__ vv,
                            unsigned short* __restrict__ Wout, float* __restrict__ bout,
                            float alpha) {
  int idx = blockIdx.x * 256 + threadIdx.x;
  if (idx < 192 * 192) {
    int o = idx / 192;
    float s = g[o] * rsqrtf(vv[o] + 1e-5f);
    Wout[idx] = f2bf(W[idx] * s * alpha);
  }
  if (idx < 192) {
    float s = g[idx] * rsqrtf(vv[idx] + 1e-5f);
    bout[idx] = (bb[idx] - mm[idx] * s) * alpha;
  }
}

// ---------------- projection: Y = relu(W' X + bias) ----------------
template <int LAYOUT>
__launch_bounds__(256)
__global__ void proj_kernel(const float* __restrict__ X,
                            const unsigned short* __restrict__ Wp,
                            const float* __restrict__ bias,
                            unsigned short* __restrict__ Yv) {
  const int o0 = blockIdx.x * 64;
  const int hw0 = blockIdx.y * 64;
  const int b = blockIdx.z;
  const int w = threadIdx.x >> 6, l = threadIdx.x & 63;
  const int l16 = l & 15, lg = l >> 4;
  const float* Xb = X + (size_t)b * 192 * 4096;

  f32x4 acc[4] = {f32x4{0,0,0,0}, f32x4{0,0,0,0}, f32x4{0,0,0,0}, f32x4{0,0,0,0}};

  for (int ks = 0; ks < 6; ++ks) {
    const int c0 = ks * 32 + lg * 8;
    bf16x8 a = *(const bf16x8*)(Wp + (size_t)(o0 + 16 * w + l16) * 192 + c0);
#pragma unroll
    for (int n = 0; n < 4; ++n) {
      const int hw = hw0 + 16 * n + l16;
      bf16x8 bfr;
#pragma unroll
      for (int j = 0; j < 8; ++j)
        bfr[j] = (short)f2bf(Xb[(size_t)(c0 + j) * 4096 + hw]);
      acc[n] = mfma16(a, bfr, acc[n]);
    }
  }

#pragma unroll
  for (int n = 0; n < 4; ++n) {
    const int hw = hw0 + 16 * n + l16;
    float vv4[4];
#pragma unroll
    for (int r = 0; r < 4; ++r) {
      const int o = o0 + 16 * w + lg * 4 + r;
      vv4[r] = fmaxf(acc[n][r] + bias[o], 0.0f);
    }
    if (LAYOUT == 1) {
      unsigned int lo = (unsigned)f2bf(vv4[0]) | ((unsigned)f2bf(vv4[1]) << 16);
      unsigned int hi = (unsigned)f2bf(vv4[2]) | ((unsigned)f2bf(vv4[3]) << 16);
      uint2 pk; pk.x = lo; pk.y = hi;
      *(uint2*)(Yv + ((size_t)b * 4096 + hw) * 192 + o0 + 16 * w + lg * 4) = pk;
    } else {
#pragma unroll
      for (int r = 0; r < 4; ++r) {
        const int o = o0 + 16 * w + lg * 4 + r;
        Yv[((size_t)b * 192 + o) * 4096 + hw] = f2bf(vv4[r]);
      }
    }
  }
}

// ---------------- final projection with NS-way partial-sum input (f32 out) ----------------
template <int NS>
__launch_bounds__(256)
__global__ void proj_sum_kernel(const float* __restrict__ X,
                                const unsigned short* __restrict__ Wp,
                                const float* __restrict__ bias,
                                float* __restrict__ Yv) {
  const int o0 = blockIdx.x * 64;
  const int hw0 = blockIdx.y * 64;
  const int b = blockIdx.z;
  const int w = threadIdx.x >> 6, l = threadIdx.x & 63;
  const int l16 = l & 15, lg = l >> 4;
  const float* Xb = X + (size_t)b * 192 * 4096;
  const size_t sstride = (size_t)4 * 192 * 4096;

  f32x4 acc[4] = {f32x4{0,0,0,0}, f32x4{0,0,0,0}, f32x4{0,0,0,0}, f32x4{0,0,0,0}};

  for (int ks = 0; ks < 6; ++ks) {
    const int c0 = ks * 32 + lg * 8;
    bf16x8 a = *(const bf16x8*)(Wp + (size_t)(o0 + 16 * w + l16) * 192 + c0);
#pragma unroll
    for (int n = 0; n < 4; ++n) {
      const int hw = hw0 + 16 * n + l16;
      bf16x8 bfr;
#pragma unroll
      for (int j = 0; j < 8; ++j) {
        float s = Xb[(size_t)(c0 + j) * 4096 + hw];
#pragma unroll
        for (int ss = 1; ss < NS; ++ss)
          s += Xb[(size_t)(c0 + j) * 4096 + hw + ss * sstride];
        bfr[j] = (short)f2bf(s);
      }
      acc[n] = mfma16(a, bfr, acc[n]);
    }
  }

#pragma unroll
  for (int n = 0; n < 4; ++n) {
    const int hw = hw0 + 16 * n + l16;
#pragma unroll
    for (int r = 0; r < 4; ++r) {
      const int o = o0 + 16 * w + lg * 4 + r;
      Yv[((size_t)b * 192 + o) * 4096 + hw] = fmaxf(acc[n][r] + bias[o], 0.0f);
    }
  }
}

// ---------------- pass 1: colsum[b][k] = sum_q exp2(S[q][k]) ----------------
__launch_bounds__(256)
__global__ void pass1_kernel(const unsigned short* __restrict__ qp,
                             const unsigned short* __restrict__ kpT,
                             float* __restrict__ colsum) {
  const int q0 = blockIdx.x * 128, k0 = blockIdx.y * 128, b = blockIdx.z;
  const int w = threadIdx.x >> 6, l = threadIdx.x & 63;
  const int l16 = l & 15, lg = l >> 4;
  const unsigned short* qb = qp + (size_t)b * 4096 * 192;
  const unsigned short* kb = kpT + (size_t)b * 4096 * 192;

  __shared__ __align__(16) unsigned short kpl[128][200];
  __shared__ float cs[4][128];

  {
    const int t = threadIdx.x;
#pragma unroll
    for (int i = 0; i < 12; ++i) {
      int idx = t + i * 256;
      int row = idx / 24, cu = idx % 24;
      uint4 vdat = *(const uint4*)(kb + (size_t)(k0 + row) * 192 + cu * 8);
      *(uint4*)&kpl[row][cu * 8] = vdat;
    }
  }
  __syncthreads();

  f32x4 acc[2][8];
#pragma unroll
  for (int m = 0; m < 2; ++m)
#pragma unroll
    for (int n = 0; n < 8; ++n) acc[m][n] = f32x4{0, 0, 0, 0};

  for (int ks = 0; ks < 6; ++ks) {
    const int c0 = ks * 32 + lg * 8;
    bf16x8 a0 = *(const bf16x8*)(qb + (size_t)(q0 + 32 * w + l16) * 192 + c0);
    bf16x8 a1 = *(const bf16x8*)(qb + (size_t)(q0 + 32 * w + 16 + l16) * 192 + c0);
#pragma unroll
    for (int n = 0; n < 8; ++n) {
      bf16x8 bfr = *(const bf16x8*)&kpl[16 * n + l16][c0];
      acc[0][n] = mfma16(a0, bfr, acc[0][n]);
      acc[1][n] = mfma16(a1, bfr, acc[1][n]);
    }
  }

  float part[8];
#pragma unroll
  for (int n = 0; n < 8; ++n) {
    float s = 0.f;
#pragma unroll
    for (int r = 0; r < 4; ++r)
      s += __builtin_amdgcn_exp2f(acc[0][n][r]) + __builtin_amdgcn_exp2f(acc[1][n][r]);
    s += __shfl_xor(s, 16);
    s += __shfl_xor(s, 32);
    part[n] = s;
  }
  if (l < 16) {
#pragma unroll
    for (int n = 0; n < 8; ++n) cs[w][16 * n + l] = part[n];
  }
  __syncthreads();
  const int t = threadIdx.x;
  if (t < 128) {
    float s = cs[0][t] + cs[1][t] + cs[2][t] + cs[3][t];
    atomicAdd(&colsum[(size_t)b * 4096 + k0 + t], s);
  }
}

__global__ void invert_kernel(float* __restrict__ p, int n) {
  int i = blockIdx.x * 256 + threadIdx.x;
  if (i < n) p[i] = 1.0f / p[i];
}

// ---------------- pass 2: K-panel LDS staging (double-buffered), 64k chunks ----------------
// grid (64 q-blocks, NS, 4 b), 512 threads = 2(m)x4(n) waves.
// Per chunk: issue next K-panel loads -> QK^T from LDS (conflict-free via XOR
// swizzle) -> exp2*rcol -> barrier -> cor LDS write + next-K LDS write ->
// barrier -> nt corr store + PV (V gathers). ss partials to private slabs.
template <int NS>
__launch_bounds__(512, 4)
__global__ void pass2_kernel(const unsigned short* __restrict__ qp,
                             const unsigned short* __restrict__ kpT,
                             const unsigned short* __restrict__ vpN,
                             const float* __restrict__ rcol,
                             float* __restrict__ corr,
                             float* __restrict__ ssP) {
  const int q0 = blockIdx.x * 64;
  const int s = blockIdx.y;
  const int b = blockIdx.z;
  const int nchunk = 64 / NS;
  const int kc0 = s * nchunk;
  const int w = threadIdx.x >> 6, l = threadIdx.x & 63;
  const int l16 = l & 15, lg = l >> 4;
  const int mw = w & 1, nw = w >> 1;  // 2x4 wave grid
  const unsigned short* qb = qp + (size_t)b * 4096 * 192;
  const unsigned short* kb = kpT + (size_t)b * 4096 * 192;
  const unsigned short* vb = vpN + (size_t)b * 192 * 4096;
  const float* rc = rcol + (size_t)b * 4096;
  float* corb = corr + (size_t)b * 4096 * 4096;
  float* ssb = ssP + (size_t)(s * 4 + b) * 192 * 4096;

  __shared__ __align__(16) unsigned short kst[2][64 * 192];  // 48 KB, XOR-swizzled
  __shared__ __align__(16) float cor[64][66];                // 16.5 KB, pad-2

  const int u0 = threadIdx.x;
  const int srow = u0 / 24 >= 64 ? 63 : u0 / 24;  // placeholder avoided below

  // preload A fragments (chunk-invariant)
  bf16x8 af[2][6];
#pragma unroll
  for (int tm = 0; tm < 2; ++tm)
#pragma unroll
    for (int ks = 0; ks < 6; ++ks)
      af[tm][ks] = *(const bf16x8*)(qb + (size_t)(q0 + 16 * (2 * mw + tm) + l16) * 192 + ks * 32 + lg * 8);

  f32x4 ssa[2][3];
#pragma unroll
  for (int tm = 0; tm < 2; ++tm)
#pragma unroll
    for (int j = 0; j < 3; ++j) ssa[tm][j] = f32x4{0, 0, 0, 0};

  // ---- prologue: stage first K panel into buf 0 ----
  {
    const int k0 = kc0 * 64;
#pragma unroll
    for (int i = 0; i < 3; ++i) {
      int u = u0 + i * 512;
      int row = u / 24, cu = u % 24;
      uint4 vdat = *(const uint4*)(kb + (size_t)(k0 + row) * 192 + cu * 8);
      *(uint4*)&kst[0][row * 192 + ((cu * 8) ^ ((row & 7) << 3))] = vdat;
    }
  }
  __syncthreads();

  const int krow = 16 * nw + l16;           // this wave's k-col within chunk
  const int kswz = (krow & 7) << 3;         // per-row XOR (ushort units)

  for (int kc = kc0; kc < kc0 + nchunk; ++kc) {
    const int k0 = kc * 64;
    const int cur = (kc - kc0) & 1;
    const bool havenext = (kc + 1 < kc0 + nchunk);

    // ---- issue next K-panel global loads (land during QK^T) ----
    uint4 stg[3];
    if (havenext) {
      const int k0n = k0 + 64;
#pragma unroll
      for (int i = 0; i < 3; ++i) {
        int u = u0 + i * 512;
        int row = u / 24, cu = u % 24;
        stg[i] = *(const uint4*)(kb + (size_t)(k0n + row) * 192 + cu * 8);
      }
    }

    // ---- QK^T from LDS: S[64q x 64k], wave tile 32q x 16k ----
    f32x4 sa[2];
    sa[0] = f32x4{0, 0, 0, 0};
    sa[1] = f32x4{0, 0, 0, 0};
    for (int ks = 0; ks < 6; ++ks) {
      const int c0 = ks * 32 + lg * 8;
      bf16x8 kf = *(const bf16x8*)&kst[cur][krow * 192 + (c0 ^ kswz)];
      sa[0] = mfma16(af[0][ks], kf, sa[0]);
      sa[1] = mfma16(af[1][ks], kf, sa[1]);
    }
    const float rcv = rc[k0 + krow];
#pragma unroll
    for (int tm = 0; tm < 2; ++tm)
#pragma unroll
      for (int r = 0; r < 4; ++r)
        sa[tm][r] = __builtin_amdgcn_exp2f(sa[tm][r]) * rcv;

    __syncthreads();  // prev chunk's cor readers done; stg loads drained

    // ---- cor LDS write + next-K LDS write ----
#pragma unroll
    for (int tm = 0; tm < 2; ++tm) {
#pragma unroll
      for (int r = 0; r < 4; ++r)
        cor[16 * (2 * mw + tm) + lg * 4 + r][krow] = sa[tm][r];
    }
    if (havenext) {
#pragma unroll
      for (int i = 0; i < 3; ++i) {
        int u = u0 + i * 512;
        int row = u / 24, cu = u % 24;
        *(uint4*)&kst[cur ^ 1][row * 192 + ((cu * 8) ^ ((row & 7) << 3))] = stg[i];
      }
    }
    __syncthreads();  // cor + next-K visible

    // ---- corr chunk -> global (row-contiguous 16B nt stores) ----
    {
#pragma unroll
      for (int it = 0; it < 2; ++it) {
        int u = u0 + it * 512;
        int row = u >> 4, seg = u & 15;
        f32x4 v4 = *(const f32x4*)&cor[row][seg * 4];
        __builtin_nontemporal_store(v4, (f32x4*)(corb + (size_t)(q0 + row) * 4096 + k0 + seg * 4));
      }
    }

    // ---- PV: ss += corr_chunk @ v ----
#pragma unroll
    for (int ks2 = 0; ks2 < 2; ++ks2) {
      const int cc = ks2 * 32 + lg * 8;
      bf16x8 pa[2];
#pragma unroll
      for (int tm = 0; tm < 2; ++tm) {
        f32x4 p0 = *(const f32x4*)&cor[16 * (2 * mw + tm) + l16][cc];
        f32x4 p1 = *(const f32x4*)&cor[16 * (2 * mw + tm) + l16][cc + 4];
#pragma unroll
        for (int j = 0; j < 4; ++j) {
          pa[tm][j] = (short)f2bf(p0[j]);
          pa[tm][j + 4] = (short)f2bf(p1[j]);
        }
      }
#pragma unroll
      for (int j = 0; j < 3; ++j) {
        const int ccol = 16 * (nw + 4 * j) + l16;
        bf16x8 bfr = *(const bf16x8*)(vb + (size_t)ccol * 4096 + k0 + cc);
        ssa[0][j] = mfma16(pa[0], bfr, ssa[0][j]);
        ssa[1][j] = mfma16(pa[1], bfr, ssa[1][j]);
      }
    }
  }

  // ---- store ss partial (transposed) into this split's private slab ----
#pragma unroll
  for (int tm = 0; tm < 2; ++tm)
#pragma unroll
    for (int j = 0; j < 3; ++j) {
      const int ccol = 16 * (nw + 4 * j) + l16;
#pragma unroll
      for (int r = 0; r < 4; ++r) {
        const int qrow = q0 + 16 * (2 * mw + tm) + lg * 4 + r;
        ssb[(size_t)ccol * 4096 + qrow] = ssa[tm][j][r];
      }
    }
}

// ---------------- launcher ----------------
extern "C" void kernel_launch(void* const* d_in, const int* in_sizes, int n_in,
                              void* d_out, int out_size, void* d_ws, size_t ws_size,
                              hipStream_t stream) {
  (void)in_sizes; (void)n_in; (void)out_size;
  const float* lr = (const float*)d_in[0];
  const float* refine = (const float*)d_in[1];

  char* ws = (char*)d_ws;
  unsigned short* w4 = (unsigned short*)(ws + 0);                       // 4*192*192 bf16
  float* bias4 = (float*)(ws + 294912);                                // 4*192 f32
  unsigned short* qp = (unsigned short*)(ws + 297984);                 // [4][4096][192] bf16
  unsigned short* kp = (unsigned short*)(ws + 297984 + 6291456);       // [4][4096][192] bf16
  unsigned short* vp = (unsigned short*)(ws + 297984 + 2 * 6291456);   // [4][192][4096] bf16
  float* colsum = (float*)(ws + 297984 + 3 * 6291456);                 // [4][4096] f32
  float* ssP = (float*)(ws + 297984 + 3 * 6291456 + 65536);            // [NS][4][192][4096] f32

  const size_t base = 297984 + (size_t)3 * 6291456 + 65536;
  const size_t slab = (size_t)4 * 192 * 4096 * 4;  // 12.58 MB per split
  int NS = (ws_size >= base + 2 * slab) ? 2 : 1;

  float* out0 = (float*)d_out;
  float* corr = out0 + 3145728;  // [4][4096][4096] f32

  const float alpha = (float)(1.4426950408889634 / sqrt(192.0));  // log2(e)/sqrt(C)

  for (int p = 0; p < 4; ++p) {
    prep_kernel<<<dim3(144), dim3(256), 0, stream>>>(
        (const float*)d_in[2 + 5 * p], (const float*)d_in[3 + 5 * p],
        (const float*)d_in[4 + 5 * p], (const float*)d_in[5 + 5 * p],
        (const float*)d_in[6 + 5 * p],
        w4 + p * 36864, bias4 + p * 192, p == 0 ? alpha : 1.0f);
  }
  hipMemsetAsync(colsum, 0, 65536, stream);

  proj_kernel<1><<<dim3(3, 64, 4), dim3(256), 0, stream>>>(refine, w4, bias4, qp);
  proj_kernel<1><<<dim3(3, 64, 4), dim3(256), 0, stream>>>(lr, w4 + 36864, bias4 + 192, kp);
  proj_kernel<0><<<dim3(3, 64, 4), dim3(256), 0, stream>>>(lr, w4 + 2 * 36864, bias4 + 2 * 192, vp);

  pass1_kernel<<<dim3(32, 32, 4), dim3(256), 0, stream>>>(qp, kp, colsum);
  invert_kernel<<<dim3(64), dim3(256), 0, stream>>>(colsum, 16384);

  if (NS == 2) {
    pass2_kernel<2><<<dim3(64, 2, 4), dim3(512), 0, stream>>>(qp, kp, vp, colsum, corr, ssP);
    proj_sum_kernel<2><<<dim3(3, 64, 4), dim3(256), 0, stream>>>(ssP, w4 + 3 * 36864, bias4 + 3 * 192, out0);
  } else {
    pass2_kernel<1><<<dim3(64, 1, 4), dim3(512), 0, stream>>>(qp, kp, vp, colsum, corr, ssP);
    proj_sum_kernel<1><<<dim3(3, 64, 4), dim3(256), 0, stream>>>(ssP, w4 + 3 * 36864, bias4 + 3 * 192, out0);
  }
}